// Round 7
// baseline (53417.957 us; speedup 1.0000x reference)
//
#include <hip/hip_runtime.h>
#include <cmath>

// Problem constants (from reference): B=64, T=512, I=512, H=1024, L=2
#define B_  64
#define T_  512
#define I_  512
#define H_  1024
#define TI_ (T_ * I_)   // x row pitch per batch (floats)
#define TH_ (T_ * H_)   // h1 row pitch per batch (floats)
#define CK  64          // K-chunk staged per LDS buffer
#define CP  65          // chunk row pitch (pad +1 -> conflict-free lane=b reads)
#define NBLK 256
#define NTHR 256

// ---------------- coherent (L1/L2-bypassing) loads for cross-XCD h data ----
__device__ __forceinline__ float ldcg(const float* p)
{
  return __hip_atomic_load(p, __ATOMIC_RELAXED, __HIP_MEMORY_SCOPE_AGENT);
}
__device__ __forceinline__ float4 ldcg4(const float* p)
{
  float4 v;
  v.x = ldcg(p + 0); v.y = ldcg(p + 1); v.z = ldcg(p + 2); v.w = ldcg(p + 3);
  return v;
}

// ---------------- distributed flag barrier (no contended RMW) ---------------
// publish: block-level sync (drains all waves' h stores to L2), then thread0
// release-stores this block's flag (wbl2 flush -> h visible at IF$ first).
__device__ __forceinline__ void publish(unsigned* flags, int bid, unsigned seq)
{
  __syncthreads();
  if (threadIdx.x == 0)
    __hip_atomic_store(&flags[bid], seq, __ATOMIC_RELEASE, __HIP_MEMORY_SCOPE_AGENT);
}

// waitall: thread tid polls flags[tid] (256 flags polled in parallel, relaxed
// agent loads = read-through, no invalidate). Optional one-time ACQUIRE for
// the layer transition (lets layer-1 use plain cached loads on h1).
__device__ __forceinline__ void waitall(unsigned* flags, unsigned target, bool acq)
{
  const int tid = threadIdx.x;
  if (tid < NBLK) {
    while (__hip_atomic_load(&flags[tid], __ATOMIC_RELAXED, __HIP_MEMORY_SCOPE_AGENT) < target)
      __builtin_amdgcn_s_sleep(1);
  }
  __syncthreads();
  if (acq) {
    if (tid == 0)
      (void)__hip_atomic_load(&flags[0], __ATOMIC_ACQUIRE, __HIP_MEMORY_SCOPE_AGENT);
    __syncthreads();
  }
}

// ---------------- per-chunk FMA: 3 weight rows, input from LDS [k][b] -------
__device__ __forceinline__ void chunk_fma(const float* cb, int b,
                                          const float* wr, const float* wz, const float* wn,
                                          float& aR, float& aZ, float& aN)
{
#pragma unroll
  for (int k4 = 0; k4 < CK / 4; ++k4) {
    float4 WR = *(const float4*)(wr + k4 * 4);
    float4 WZ = *(const float4*)(wz + k4 * 4);
    float4 WN = *(const float4*)(wn + k4 * 4);
    float v0 = cb[(k4 * 4 + 0) * CP + b];
    float v1 = cb[(k4 * 4 + 1) * CP + b];
    float v2 = cb[(k4 * 4 + 2) * CP + b];
    float v3 = cb[(k4 * 4 + 3) * CP + b];
    aR = fmaf(WR.x, v0, aR); aZ = fmaf(WZ.x, v0, aZ); aN = fmaf(WN.x, v0, aN);
    aR = fmaf(WR.y, v1, aR); aZ = fmaf(WZ.y, v1, aZ); aN = fmaf(WN.y, v1, aN);
    aR = fmaf(WR.z, v2, aR); aZ = fmaf(WZ.z, v2, aZ); aN = fmaf(WN.z, v2, aN);
    aR = fmaf(WR.w, v3, aR); aZ = fmaf(WZ.w, v3, aZ); aN = fmaf(WN.w, v3, aN);
  }
}

__device__ __forceinline__ void stage_store(float* cbw, int q4, int r0,
                                            const float4& pf0, const float4& pf1,
                                            const float4& pf2, const float4& pf3)
{
  cbw[(q4 + 0) * CP + (r0 +  0)] = pf0.x;
  cbw[(q4 + 1) * CP + (r0 +  0)] = pf0.y;
  cbw[(q4 + 2) * CP + (r0 +  0)] = pf0.z;
  cbw[(q4 + 3) * CP + (r0 +  0)] = pf0.w;
  cbw[(q4 + 0) * CP + (r0 + 16)] = pf1.x;
  cbw[(q4 + 1) * CP + (r0 + 16)] = pf1.y;
  cbw[(q4 + 2) * CP + (r0 + 16)] = pf1.z;
  cbw[(q4 + 3) * CP + (r0 + 16)] = pf1.w;
  cbw[(q4 + 0) * CP + (r0 + 32)] = pf2.x;
  cbw[(q4 + 1) * CP + (r0 + 32)] = pf2.y;
  cbw[(q4 + 2) * CP + (r0 + 32)] = pf2.z;
  cbw[(q4 + 3) * CP + (r0 + 32)] = pf2.w;
  cbw[(q4 + 0) * CP + (r0 + 48)] = pf3.x;
  cbw[(q4 + 1) * CP + (r0 + 48)] = pf3.y;
  cbw[(q4 + 2) * CP + (r0 + 48)] = pf3.z;
  cbw[(q4 + 3) * CP + (r0 + 48)] = pf3.w;
}

// Process nchunks K-chunks from src (per-batch pitch `pitch`), double-buffered
// through LDS with one-chunk-ahead global prefetch. COH=true -> coherent
// (cache-bypass) loads for cross-XCD h data; COH=false -> plain cached float4.
template <bool COH>
__device__ __forceinline__ void phase_chunks(float (*chunk)[CK * CP], int nchunks,
                                             const float* src, size_t pitch,
                                             const float* wr, const float* wz, const float* wn,
                                             float& aR, float& aZ, float& aN,
                                             int q4, int r0, int b)
{
  auto LD4 = [](const float* p) -> float4 {
    if constexpr (COH) return ldcg4(p);
    else               return *(const float4*)p;
  };

  float4 pf0, pf1, pf2, pf3;
  {
    const float* p = src + q4;
    pf0 = LD4(p + (size_t)(r0 +  0) * pitch);
    pf1 = LD4(p + (size_t)(r0 + 16) * pitch);
    pf2 = LD4(p + (size_t)(r0 + 32) * pitch);
    pf3 = LD4(p + (size_t)(r0 + 48) * pitch);
  }
  for (int c = 0; c < nchunks; ++c) {
    stage_store(chunk[c & 1], q4, r0, pf0, pf1, pf2, pf3);
    if (c + 1 < nchunks) {
      const float* p = src + (c + 1) * CK + q4;
      pf0 = LD4(p + (size_t)(r0 +  0) * pitch);
      pf1 = LD4(p + (size_t)(r0 + 16) * pitch);
      pf2 = LD4(p + (size_t)(r0 + 32) * pitch);
      pf3 = LD4(p + (size_t)(r0 + 48) * pitch);
    }
    __syncthreads();
    chunk_fma(chunk[c & 1], b, wr + c * CK, wz + c * CK, wn + c * CK, aR, aZ, aN);
  }
}

__global__ void __launch_bounds__(NTHR)
gru_fused(const float* __restrict__ x,
          const float* __restrict__ wih0, const float* __restrict__ whh0,
          const float* __restrict__ bih0, const float* __restrict__ bhh0,
          const float* __restrict__ wih1, const float* __restrict__ whh1,
          const float* __restrict__ bih1, const float* __restrict__ bhh1,
          float* __restrict__ h1, float* __restrict__ hb0, float* __restrict__ hb1,
          unsigned* __restrict__ flags, float* __restrict__ out)
{
  __shared__ float chunk[2][CK * CP];

  const int tid = threadIdx.x;
  const int b   = tid & 63;                                   // lane = batch row
  const int jj  = __builtin_amdgcn_readfirstlane(tid >> 6);   // wave id, uniform
  const int bid = blockIdx.x;
  const int j   = bid * 4 + jj;                               // owned h column
  const int q4  = (tid & 15) * 4;                             // staging k offset
  const int r0  = tid >> 4;                                   // staging base row

  for (int layer = 0; layer < 2; ++layer) {
    const int Ki  = layer ? H_ : I_;
    const int NCX = Ki / CK;        // x-part chunks (8 or 16)
    const int NCH = H_ / CK;        // h-part chunks (16)

    const float* wih = layer ? wih1 : wih0;
    const float* whh = layer ? whh1 : whh0;
    const float* bih = layer ? bih1 : bih0;
    const float* bhh = layer ? bhh1 : bhh0;

    const float* wxr = wih + (size_t)(0 * H_ + j) * Ki;
    const float* wxz = wih + (size_t)(1 * H_ + j) * Ki;
    const float* wxn = wih + (size_t)(2 * H_ + j) * Ki;
    const float* whr = whh + (size_t)(0 * H_ + j) * H_;
    const float* whz = whh + (size_t)(1 * H_ + j) * H_;
    const float* whn = whh + (size_t)(2 * H_ + j) * H_;

    const float bR  = bih[j] + bhh[j];
    const float bZ  = bih[H_ + j] + bhh[H_ + j];
    const float bXN = bih[2 * H_ + j];
    const float bHN = bhh[2 * H_ + j];

    float hreg = 0.0f;  // h(b, j) lives in a register for the whole scan

    for (int t = 0; t < T_; ++t) {
      float accR = bR, accZ = bZ, accXN = bXN, accHN = bHN;

      // layer transition: ONE acquire so layer-1 can read h1 with cached loads
      if (layer == 1 && t == 0) waitall(flags, (unsigned)T_, /*acq=*/true);

      // ---- x-phase: independent of h(t-1); overlaps other blocks' publishes.
      // Cached loads (x is input; h1 is stable after the transition acquire).
      const float* xsrc = layer ? (h1 + (size_t)t * H_) : (x + (size_t)t * I_);
      const size_t xpit = layer ? (size_t)TH_ : (size_t)TI_;
      phase_chunks<false>(chunk, NCX, xsrc, xpit, wxr, wxz, wxn,
                          accR, accZ, accXN, q4, r0, b);

      // ---- h-phase: needs all blocks' h(t-1); coherent (bypass) loads so no
      // per-step cache invalidation is needed -> weights stay hot in L2.
      if (t > 0) {
        waitall(flags, (unsigned)(layer * T_ + t), /*acq=*/false);
        const float* hsrc = layer ? ((t & 1) ? hb0 : hb1)
                                  : (h1 + (size_t)(t - 1) * H_);
        const size_t hpit = layer ? (size_t)H_ : (size_t)TH_;
        phase_chunks<true>(chunk, NCH, hsrc, hpit, whr, whz, whn,
                           accR, accZ, accHN, q4, r0, b);
      }

      // gates
      const float r = 1.0f / (1.0f + expf(-accR));
      const float z = 1.0f / (1.0f + expf(-accZ));
      const float n = tanhf(accXN + r * accHN);
      const float hnew = (1.0f - z) * n + z * hreg;
      hreg = hnew;

      if (layer == 0) {
        h1[(size_t)b * TH_ + (size_t)t * H_ + j] = hnew;
      } else {
        ((t & 1) ? hb1 : hb0)[b * H_ + j] = hnew;
        if (t == T_ - 1) out[b * H_ + j] = hnew;
      }

      if (!(layer == 1 && t == T_ - 1))
        publish(flags, bid, (unsigned)(layer * T_ + t + 1));
    }
  }
}

extern "C" void kernel_launch(void* const* d_in, const int* in_sizes, int n_in,
                              void* d_out, int out_size, void* d_ws, size_t ws_size,
                              hipStream_t stream)
{
  const float* x    = (const float*)d_in[0];
  const float* wih0 = (const float*)d_in[1];
  const float* whh0 = (const float*)d_in[2];
  const float* bih0 = (const float*)d_in[3];
  const float* bhh0 = (const float*)d_in[4];
  const float* wih1 = (const float*)d_in[5];
  const float* whh1 = (const float*)d_in[6];
  const float* bih1 = (const float*)d_in[7];
  const float* bhh1 = (const float*)d_in[8];
  float* out = (float*)d_out;

  // workspace: h1 (B*T*H) | hb0 (B*H) | hb1 (B*H) | flags[NBLK]
  float* h1  = (float*)d_ws;
  float* hb0 = h1 + (size_t)B_ * T_ * H_;
  float* hb1 = hb0 + (size_t)B_ * H_;
  unsigned* flags = (unsigned*)(hb1 + (size_t)B_ * H_);

  // flags must start at 0 (harness poisons ws with 0xAA)
  hipMemsetAsync(flags, 0, NBLK * sizeof(unsigned), stream);

  void* args[] = { (void*)&x,
                   (void*)&wih0, (void*)&whh0, (void*)&bih0, (void*)&bhh0,
                   (void*)&wih1, (void*)&whh1, (void*)&bih1, (void*)&bhh1,
                   (void*)&h1, (void*)&hb0, (void*)&hb1, (void*)&flags, (void*)&out };

  hipLaunchCooperativeKernel((const void*)gru_fused,
                             dim3(NBLK), dim3(NTHR), args, 0, stream);
}

// Round 8
// 43026.175 us; speedup vs baseline: 1.2415x; 1.2415x over previous
//
#include <hip/hip_runtime.h>
#include <cmath>

// Problem constants (from reference): B=64, T=512, I=512, H=1024, L=2
#define B_  64
#define T_  512
#define I_  512
#define H_  1024
#define TI_ (T_ * I_)   // x row pitch per batch (floats)
#define TH_ (T_ * H_)   // h1 row pitch per batch (floats)
#define CK  64          // K-chunk staged per LDS buffer
#define CP  65          // chunk row pitch (pad +1 -> conflict-free lane=b reads)
#define NBLK 256
#define NTHR 256

// ---- coherent primitives (agent scope => sc1 => bypass per-XCD L2) ---------
__device__ __forceinline__ void stcg(float* p, float v)
{
  __hip_atomic_store(p, v, __ATOMIC_RELAXED, __HIP_MEMORY_SCOPE_AGENT);
}

// issue 4 coherent 16B loads (no wait) -- results valid only after vmcnt(0)
__device__ __forceinline__ void issue4(const float* p0, const float* p1,
                                       const float* p2, const float* p3,
                                       float4& f0, float4& f1, float4& f2, float4& f3)
{
  asm volatile(
    "global_load_dwordx4 %0, %4, off sc0 sc1\n\t"
    "global_load_dwordx4 %1, %5, off sc0 sc1\n\t"
    "global_load_dwordx4 %2, %6, off sc0 sc1\n\t"
    "global_load_dwordx4 %3, %7, off sc0 sc1"
    : "=&v"(f0), "=&v"(f1), "=&v"(f2), "=&v"(f3)
    : "v"(p0), "v"(p1), "v"(p2), "v"(p3));
}

// ---- zero-fence distributed flag barrier -----------------------------------
// publish: each thread already issued its (sc1) h store; vmcnt(0) acks it at
// the coherence point, block sync proves all threads done, then thread0
// relaxed-stores this block's flag (sc1). NO wbl2, NO inv.
__device__ __forceinline__ void publish(unsigned* flags, int bid, unsigned seq)
{
  asm volatile("s_waitcnt vmcnt(0)" ::: "memory");
  __syncthreads();
  if (threadIdx.x == 0)
    __hip_atomic_store(&flags[bid], seq, __ATOMIC_RELAXED, __HIP_MEMORY_SCOPE_AGENT);
}

// waitall: thread tid polls flags[tid] (256 flags in parallel, relaxed sc1
// loads). Optional one-time ACQUIRE (layer transition only).
__device__ __forceinline__ void waitall(unsigned* flags, unsigned target, bool acq)
{
  const int tid = threadIdx.x;
  if (tid < NBLK) {
    while (__hip_atomic_load(&flags[tid], __ATOMIC_RELAXED, __HIP_MEMORY_SCOPE_AGENT) < target)
      __builtin_amdgcn_s_sleep(1);
  }
  __syncthreads();
  if (acq) {
    if (tid == 0)
      (void)__hip_atomic_load(&flags[0], __ATOMIC_ACQUIRE, __HIP_MEMORY_SCOPE_AGENT);
    __syncthreads();
  }
}

// ---- per-chunk FMA: 3 weight rows, input from LDS [k][b] -------------------
__device__ __forceinline__ void chunk_fma(const float* cb, int b,
                                          const float* wr, const float* wz, const float* wn,
                                          float& aR, float& aZ, float& aN)
{
#pragma unroll
  for (int k4 = 0; k4 < CK / 4; ++k4) {
    float4 WR = *(const float4*)(wr + k4 * 4);
    float4 WZ = *(const float4*)(wz + k4 * 4);
    float4 WN = *(const float4*)(wn + k4 * 4);
    float v0 = cb[(k4 * 4 + 0) * CP + b];
    float v1 = cb[(k4 * 4 + 1) * CP + b];
    float v2 = cb[(k4 * 4 + 2) * CP + b];
    float v3 = cb[(k4 * 4 + 3) * CP + b];
    aR = fmaf(WR.x, v0, aR); aZ = fmaf(WZ.x, v0, aZ); aN = fmaf(WN.x, v0, aN);
    aR = fmaf(WR.y, v1, aR); aZ = fmaf(WZ.y, v1, aZ); aN = fmaf(WN.y, v1, aN);
    aR = fmaf(WR.z, v2, aR); aZ = fmaf(WZ.z, v2, aZ); aN = fmaf(WN.z, v2, aN);
    aR = fmaf(WR.w, v3, aR); aZ = fmaf(WZ.w, v3, aZ); aN = fmaf(WN.w, v3, aN);
  }
}

__device__ __forceinline__ void stage_store(float* cbw, int q4, int r0,
                                            const float4& pf0, const float4& pf1,
                                            const float4& pf2, const float4& pf3)
{
  cbw[(q4 + 0) * CP + (r0 +  0)] = pf0.x;
  cbw[(q4 + 1) * CP + (r0 +  0)] = pf0.y;
  cbw[(q4 + 2) * CP + (r0 +  0)] = pf0.z;
  cbw[(q4 + 3) * CP + (r0 +  0)] = pf0.w;
  cbw[(q4 + 0) * CP + (r0 + 16)] = pf1.x;
  cbw[(q4 + 1) * CP + (r0 + 16)] = pf1.y;
  cbw[(q4 + 2) * CP + (r0 + 16)] = pf1.z;
  cbw[(q4 + 3) * CP + (r0 + 16)] = pf1.w;
  cbw[(q4 + 0) * CP + (r0 + 32)] = pf2.x;
  cbw[(q4 + 1) * CP + (r0 + 32)] = pf2.y;
  cbw[(q4 + 2) * CP + (r0 + 32)] = pf2.z;
  cbw[(q4 + 3) * CP + (r0 + 32)] = pf2.w;
  cbw[(q4 + 0) * CP + (r0 + 48)] = pf3.x;
  cbw[(q4 + 1) * CP + (r0 + 48)] = pf3.y;
  cbw[(q4 + 2) * CP + (r0 + 48)] = pf3.z;
  cbw[(q4 + 3) * CP + (r0 + 48)] = pf3.w;
}

// Process nchunks K-chunks from src (per-batch pitch `pitch`), double-buffered
// through LDS with one-chunk-ahead prefetch.
// COH=false: plain cached float4 loads (x / stable h1).
// COH=true : coherent vector loads via issue4 + explicit vmcnt(0) consume.
template <bool COH>
__device__ __forceinline__ void phase_chunks(float (*chunk)[CK * CP], int nchunks,
                                             const float* src, size_t pitch,
                                             const float* wr, const float* wz, const float* wn,
                                             float& aR, float& aZ, float& aN,
                                             int q4, int r0, int b)
{
  float4 pf0, pf1, pf2, pf3;
  if constexpr (COH) {
    const float* p = src + q4;
    issue4(p + (size_t)(r0 +  0) * pitch, p + (size_t)(r0 + 16) * pitch,
           p + (size_t)(r0 + 32) * pitch, p + (size_t)(r0 + 48) * pitch,
           pf0, pf1, pf2, pf3);
    for (int c = 0; c < nchunks; ++c) {
      // loads issued for chunk c are now required: wait, then LDS-store.
      asm volatile("s_waitcnt vmcnt(0)" ::: "memory");
      __builtin_amdgcn_sched_barrier(0);
      stage_store(chunk[c & 1], q4, r0, pf0, pf1, pf2, pf3);
      if (c + 1 < nchunks) {
        const float* pn = src + (c + 1) * CK + q4;
        issue4(pn + (size_t)(r0 +  0) * pitch, pn + (size_t)(r0 + 16) * pitch,
               pn + (size_t)(r0 + 32) * pitch, pn + (size_t)(r0 + 48) * pitch,
               pf0, pf1, pf2, pf3);   // overlaps with chunk_fma below
      }
      __syncthreads();
      chunk_fma(chunk[c & 1], b, wr + c * CK, wz + c * CK, wn + c * CK, aR, aZ, aN);
    }
  } else {
    {
      const float* p = src + q4;
      pf0 = *(const float4*)(p + (size_t)(r0 +  0) * pitch);
      pf1 = *(const float4*)(p + (size_t)(r0 + 16) * pitch);
      pf2 = *(const float4*)(p + (size_t)(r0 + 32) * pitch);
      pf3 = *(const float4*)(p + (size_t)(r0 + 48) * pitch);
    }
    for (int c = 0; c < nchunks; ++c) {
      stage_store(chunk[c & 1], q4, r0, pf0, pf1, pf2, pf3);
      if (c + 1 < nchunks) {
        const float* p = src + (c + 1) * CK + q4;
        pf0 = *(const float4*)(p + (size_t)(r0 +  0) * pitch);
        pf1 = *(const float4*)(p + (size_t)(r0 + 16) * pitch);
        pf2 = *(const float4*)(p + (size_t)(r0 + 32) * pitch);
        pf3 = *(const float4*)(p + (size_t)(r0 + 48) * pitch);
      }
      __syncthreads();
      chunk_fma(chunk[c & 1], b, wr + c * CK, wz + c * CK, wn + c * CK, aR, aZ, aN);
    }
  }
}

__global__ void __launch_bounds__(NTHR)
gru_fused(const float* __restrict__ x,
          const float* __restrict__ wih0, const float* __restrict__ whh0,
          const float* __restrict__ bih0, const float* __restrict__ bhh0,
          const float* __restrict__ wih1, const float* __restrict__ whh1,
          const float* __restrict__ bih1, const float* __restrict__ bhh1,
          float* __restrict__ h1, float* __restrict__ hb0, float* __restrict__ hb1,
          unsigned* __restrict__ flags, float* __restrict__ out)
{
  __shared__ float chunk[2][CK * CP];

  const int tid = threadIdx.x;
  const int b   = tid & 63;                                   // lane = batch row
  const int jj  = __builtin_amdgcn_readfirstlane(tid >> 6);   // wave id, uniform
  const int bid = blockIdx.x;
  const int j   = bid * 4 + jj;                               // owned h column
  const int q4  = (tid & 15) * 4;                             // staging k offset
  const int r0  = tid >> 4;                                   // staging base row

  for (int layer = 0; layer < 2; ++layer) {
    const int Ki  = layer ? H_ : I_;
    const int NCX = Ki / CK;        // x-part chunks (8 or 16)
    const int NCH = H_ / CK;        // h-part chunks (16)

    const float* wih = layer ? wih1 : wih0;
    const float* whh = layer ? whh1 : whh0;
    const float* bih = layer ? bih1 : bih0;
    const float* bhh = layer ? bhh1 : bhh0;

    const float* wxr = wih + (size_t)(0 * H_ + j) * Ki;
    const float* wxz = wih + (size_t)(1 * H_ + j) * Ki;
    const float* wxn = wih + (size_t)(2 * H_ + j) * Ki;
    const float* whr = whh + (size_t)(0 * H_ + j) * H_;
    const float* whz = whh + (size_t)(1 * H_ + j) * H_;
    const float* whn = whh + (size_t)(2 * H_ + j) * H_;

    const float bR  = bih[j] + bhh[j];
    const float bZ  = bih[H_ + j] + bhh[H_ + j];
    const float bXN = bih[2 * H_ + j];
    const float bHN = bhh[2 * H_ + j];

    float hreg = 0.0f;  // h(b, j) lives in a register for the whole scan

    for (int t = 0; t < T_; ++t) {
      float accR = bR, accZ = bZ, accXN = bXN, accHN = bHN;

      // layer transition: ONE acquire so layer-1 can read h1 with cached loads
      if (layer == 1 && t == 0) waitall(flags, (unsigned)T_, /*acq=*/true);

      // ---- x-phase: independent of h(t-1); overlaps other blocks' publishes.
      const float* xsrc = layer ? (h1 + (size_t)t * H_) : (x + (size_t)t * I_);
      const size_t xpit = layer ? (size_t)TH_ : (size_t)TI_;
      phase_chunks<false>(chunk, NCX, xsrc, xpit, wxr, wxz, wxn,
                          accR, accZ, accXN, q4, r0, b);

      // ---- h-phase: needs all blocks' h(t-1); coherent vector loads (no
      // cache maintenance anywhere -> weights stay hot in L2 all scan long).
      if (t > 0) {
        waitall(flags, (unsigned)(layer * T_ + t), /*acq=*/false);
        const float* hsrc = layer ? ((t & 1) ? hb0 : hb1)
                                  : (h1 + (size_t)(t - 1) * H_);
        const size_t hpit = layer ? (size_t)H_ : (size_t)TH_;
        phase_chunks<true>(chunk, NCH, hsrc, hpit, whr, whz, whn,
                           accR, accZ, accHN, q4, r0, b);
      }

      // gates
      const float r = 1.0f / (1.0f + expf(-accR));
      const float z = 1.0f / (1.0f + expf(-accZ));
      const float n = tanhf(accXN + r * accHN);
      const float hnew = (1.0f - z) * n + z * hreg;
      hreg = hnew;

      // h store: coherent (sc1) -> lands at IF$; no dirty L2 line created.
      if (layer == 0) {
        stcg(&h1[(size_t)b * TH_ + (size_t)t * H_ + j], hnew);
      } else {
        stcg(&((t & 1) ? hb1 : hb0)[b * H_ + j], hnew);
        if (t == T_ - 1) out[b * H_ + j] = hnew;   // cached; end-of-kernel flush
      }

      if (!(layer == 1 && t == T_ - 1))
        publish(flags, bid, (unsigned)(layer * T_ + t + 1));
    }
  }
}

extern "C" void kernel_launch(void* const* d_in, const int* in_sizes, int n_in,
                              void* d_out, int out_size, void* d_ws, size_t ws_size,
                              hipStream_t stream)
{
  const float* x    = (const float*)d_in[0];
  const float* wih0 = (const float*)d_in[1];
  const float* whh0 = (const float*)d_in[2];
  const float* bih0 = (const float*)d_in[3];
  const float* bhh0 = (const float*)d_in[4];
  const float* wih1 = (const float*)d_in[5];
  const float* whh1 = (const float*)d_in[6];
  const float* bih1 = (const float*)d_in[7];
  const float* bhh1 = (const float*)d_in[8];
  float* out = (float*)d_out;

  // workspace: h1 (B*T*H) | hb0 (B*H) | hb1 (B*H) | flags[NBLK]
  float* h1  = (float*)d_ws;
  float* hb0 = h1 + (size_t)B_ * T_ * H_;
  float* hb1 = hb0 + (size_t)B_ * H_;
  unsigned* flags = (unsigned*)(hb1 + (size_t)B_ * H_);

  // flags must start at 0 (harness poisons ws with 0xAA)
  hipMemsetAsync(flags, 0, NBLK * sizeof(unsigned), stream);

  void* args[] = { (void*)&x,
                   (void*)&wih0, (void*)&whh0, (void*)&bih0, (void*)&bhh0,
                   (void*)&wih1, (void*)&whh1, (void*)&bih1, (void*)&bhh1,
                   (void*)&h1, (void*)&hb0, (void*)&hb1, (void*)&flags, (void*)&out };

  hipLaunchCooperativeKernel((const void*)gru_fused,
                             dim3(NBLK), dim3(NTHR), args, 0, stream);
}